// Round 7
// baseline (119.002 us; speedup 1.0000x reference)
//
#include <hip/hip_runtime.h>
#include <math.h>

#define VOCAB 4096
#define NROWS 65536          // B*L = 4*16384
#define DECAYF 0.99f
#define EPSF 1e-5f
#define NSEG 8               // segment-sum privatization blocks

typedef unsigned long long u64;
typedef unsigned int u32;

// ---------------- ws layout (floats) ----------------
// [0,      16384)   pack float4 (-2e0,-2e1,-2e2,e2sum)
// [16384,  49152)   pcnt[NSEG][4096]
// [49152,  147456)  pw[NSEG][12288]
// [147456, 149504)  errpart: 1024 doubles
// [149504, 149506)  n_acc double
// ~598 KB (proven ws >= 655 KB in round 4)

__global__ __launch_bounds__(256) void prep_kernel(const float* __restrict__ embed,
                                                   float4* __restrict__ pack,
                                                   double* __restrict__ n_acc) {
    #pragma clang fp contract(off)
    int v = blockIdx.x * 256 + threadIdx.x;
    if (v == 0) *n_acc = 0.0;
    if (v >= VOCAB) return;
    float e0 = embed[v * 3 + 0];
    float e1 = embed[v * 3 + 1];
    float e2 = embed[v * 3 + 2];
    // numpy rounding: (e0^2 + e1^2) + e2^2, each product rounded
    float e2s = (e0 * e0 + e1 * e1) + e2 * e2;
    // -2*e: exact pow2 scaling, commutes with the RN fma chain
    pack[v] = make_float4(-2.0f * e0, -2.0f * e1, -2.0f * e2, e2s);
}

// Scalar-path scan: block=512 (8 waves), grid=1024 (4 blocks/CU, 32 waves/CU).
// Lane owns 1 row; wave w scans cands [w*512,(w+1)*512) via wave-uniform
// float4 loads (SGPR candidates via s_load; VALU uses them as the one legal
// SGPR operand). No LDS table -> LDS pipe idle; table re-reads hit L2 (~67MB
// total, ~2us). Exact np.argmin via u64 keys; 4KB LDS merge across waves.
__global__ __launch_bounds__(512, 8) void vq_scan_kernel(
    const float* __restrict__ feats,
    const float4* __restrict__ pack,
    float* __restrict__ quant_out,
    float* __restrict__ idx_out,
    double* __restrict__ errpart) {
    #pragma clang fp contract(off)
    __shared__ u64 mk[8][64];              // 4 KB merge scratch

    const int tid  = threadIdx.x;
    const int wave = __builtin_amdgcn_readfirstlane(tid >> 6);
    const int lane = tid & 63;
    const int row  = blockIdx.x * 64 + lane;

    const float f0 = feats[row * 3 + 0];
    const float f1 = feats[row * 3 + 1];
    const float f2 = feats[row * 3 + 2];
    const float fs = (f0 * f0 + f1 * f1) + f2 * f2;   // numpy rounding

    const float4* __restrict__ wsl = pack + (wave << 9);   // uniform slice base

    float best = INFINITY;
    int   bidx = 0;

    // prefetch group 0 (4 candidates = 64 B uniform)
    float4 c0 = wsl[0], c1 = wsl[1], c2 = wsl[2], c3 = wsl[3];

    for (int g = 0; g < 128; ++g) {
        const int nj = ((g + 1) & 127) << 2;   // wrap: last prefetch re-reads g0
        float4 n0 = wsl[nj + 0];
        float4 n1 = wsl[nj + 1];
        float4 n2 = wsl[nj + 2];
        float4 n3 = wsl[nj + 3];
        const int j = g << 2;                  // uniform (SGPR) candidate index
        {
            float t = fmaf(c0.z, f2, fmaf(c0.y, f1, c0.x * f0));
            float d = (fs + t) + c0.w;         // == (fsum - 2*dot) + e2sum
            if (d < best) { best = d; bidx = j; }       // strict <: lowest j
        }
        {
            float t = fmaf(c1.z, f2, fmaf(c1.y, f1, c1.x * f0));
            float d = (fs + t) + c1.w;
            if (d < best) { best = d; bidx = j + 1; }
        }
        {
            float t = fmaf(c2.z, f2, fmaf(c2.y, f1, c2.x * f0));
            float d = (fs + t) + c2.w;
            if (d < best) { best = d; bidx = j + 2; }
        }
        {
            float t = fmaf(c3.z, f2, fmaf(c3.y, f1, c3.x * f0));
            float d = (fs + t) + c3.w;
            if (d < best) { best = d; bidx = j + 3; }
        }
        c0 = n0; c1 = n1; c2 = n2; c3 = n3;
    }

    // exact-order key: monotone(dist) high 32, global cand low 32
    u32 b  = __float_as_uint(best);
    u32 mb = b ^ ((u32)((int)b >> 31) | 0x80000000u);   // total-order map
    u64 key = ((u64)mb << 32) | (u32)((wave << 9) + bidx);

    if (wave != 0) mk[wave][lane] = key;
    __syncthreads();
    if (wave == 0) {
        #pragma unroll
        for (int w = 1; w < 8; ++w) {
            u64 k = mk[w][lane];
            key = k < key ? k : key;
        }
        const u32 cand = (u32)key;

        idx_out[row] = (float)cand;
        const float4 p = pack[cand];           // L2 gather
        const float q0 = -0.5f * p.x;          // exact recovery of e
        const float q1 = -0.5f * p.y;
        const float q2 = -0.5f * p.z;
        quant_out[row * 3 + 0] = q0;
        quant_out[row * 3 + 1] = q1;
        quant_out[row * 3 + 2] = q2;

        const float d0 = q0 - f0, d1 = q1 - f1, d2 = q2 - f2;
        float err = d0 * d0 + d1 * d1 + d2 * d2;
        #pragma unroll
        for (int off = 32; off >= 1; off >>= 1) err += __shfl_xor(err, off);
        if (lane == 0) errpart[blockIdx.x] = (double)err;
    }
}

// segment sums via LDS privatization: NSEG blocks x 1024 thr, each block
// accumulates 8192 rows into 64KB LDS (ds_add_f32), flushes plain stores.
__global__ __launch_bounds__(1024) void seg_kernel(
    const float* __restrict__ feats,
    const float* __restrict__ idx_f,
    float* __restrict__ pcnt,
    float* __restrict__ pw) {
    __shared__ float lcnt[VOCAB];          // 16 KB
    __shared__ float lw[VOCAB * 3];        // 48 KB
    const int t = threadIdx.x;
    const int b = blockIdx.x;

    #pragma unroll
    for (int i = 0; i < 4; ++i)  lcnt[t + i * 1024] = 0.0f;
    #pragma unroll
    for (int i = 0; i < 12; ++i) lw[t + i * 1024] = 0.0f;
    __syncthreads();

    #pragma unroll
    for (int i = 0; i < 8; ++i) {
        const int row = b * 8192 + i * 1024 + t;
        const int cand = (int)idx_f[row];
        const float f0 = feats[row * 3 + 0];
        const float f1 = feats[row * 3 + 1];
        const float f2 = feats[row * 3 + 2];
        atomicAdd(&lcnt[cand], 1.0f);
        atomicAdd(&lw[cand * 3 + 0], f0);
        atomicAdd(&lw[cand * 3 + 1], f1);
        atomicAdd(&lw[cand * 3 + 2], f2);
    }
    __syncthreads();

    #pragma unroll
    for (int i = 0; i < 4; ++i)  pcnt[b * VOCAB + t + i * 1024] = lcnt[t + i * 1024];
    #pragma unroll
    for (int i = 0; i < 12; ++i) pw[b * VOCAB * 3 + t + i * 1024] = lw[t + i * 1024];
}

__global__ __launch_bounds__(256) void ema_kernel(
    const float* __restrict__ ema_cs,
    const float* __restrict__ ema_w,
    const float* __restrict__ pcnt,
    const float* __restrict__ pw,
    float* __restrict__ ncs_out,
    float* __restrict__ nw_out,
    double* __restrict__ n_acc) {
    int v = blockIdx.x * 256 + threadIdx.x;
    if (v >= VOCAB) return;
    float c = 0.0f, w0 = 0.0f, w1 = 0.0f, w2 = 0.0f;
    for (int b = 0; b < NSEG; ++b) {       // ascending b = ascending row order
        c  += pcnt[b * VOCAB + v];
        w0 += pw[b * VOCAB * 3 + v * 3 + 0];
        w1 += pw[b * VOCAB * 3 + v * 3 + 1];
        w2 += pw[b * VOCAB * 3 + v * 3 + 2];
    }
    float ncs = DECAYF * ema_cs[v] + (1.0f - DECAYF) * c;
    ncs_out[v] = ncs;
    nw_out[v * 3 + 0] = DECAYF * ema_w[v * 3 + 0] + (1.0f - DECAYF) * w0;
    nw_out[v * 3 + 1] = DECAYF * ema_w[v * 3 + 1] + (1.0f - DECAYF) * w1;
    nw_out[v * 3 + 2] = DECAYF * ema_w[v * 3 + 2] + (1.0f - DECAYF) * w2;

    float s = ncs;
    #pragma unroll
    for (int off = 32; off >= 1; off >>= 1) s += __shfl_xor(s, off);
    if ((threadIdx.x & 63) == 0) atomicAdd(n_acc, (double)s);
}

__global__ __launch_bounds__(256) void final_kernel(
    const float* __restrict__ ncs,
    const float* __restrict__ nw,
    const double* __restrict__ n_acc,
    const double* __restrict__ errpart,
    float* __restrict__ embed_out,
    float* __restrict__ loss_out) {
    __shared__ double se[256];
    int v = blockIdx.x * 256 + threadIdx.x;
    if (v < VOCAB) {
        const float n = (float)(*n_acc);
        const float cs = (ncs[v] + EPSF) / (n + (float)VOCAB * EPSF) * n;
        const float d0 = nw[v * 3 + 0] / cs;
        const float d1 = nw[v * 3 + 1] / cs;
        const float d2 = nw[v * 3 + 2] / cs;
        const float nrm = fmaxf(sqrtf(d1 * d1 + d2 * d2), EPSF);
        embed_out[v * 3 + 0] = d0;
        embed_out[v * 3 + 1] = d1 / nrm;
        embed_out[v * 3 + 2] = d2 / nrm;
    }
    if (blockIdx.x == 0) {
        const int t = threadIdx.x;
        se[t] = errpart[t] + errpart[t + 256] + errpart[t + 512] + errpart[t + 768];
        __syncthreads();
        #pragma unroll
        for (int s = 128; s > 0; s >>= 1) {
            if (t < s) se[t] += se[t + s];
            __syncthreads();
        }
        if (t == 0)
            loss_out[0] = (float)(1.25 * se[0] / (double)(NROWS * 3));
    }
}

extern "C" void kernel_launch(void* const* d_in, const int* in_sizes, int n_in,
                              void* d_out, int out_size, void* d_ws, size_t ws_size,
                              hipStream_t stream) {
    const float* feats  = (const float*)d_in[0];   // 65536*3
    const float* embed  = (const float*)d_in[1];   // 4096*3
    const float* ema_cs = (const float*)d_in[2];   // 4096
    const float* ema_w  = (const float*)d_in[3];   // 4096*3

    float* out = (float*)d_out;
    float* quant_out = out;                         // 196608
    float* idx_out   = out + 196608;                // 65536
    float* loss_out  = out + 262144;                // 1
    float* embed_out = out + 262145;                // 12288
    float* ncs_out   = out + 274433;                // 4096
    float* nw_out    = out + 278529;                // 12288

    float* ws = (float*)d_ws;
    float4* pack    = (float4*)ws;                  // floats [0, 16384)
    float*  pcnt    = ws + 16384;                   // NSEG*4096
    float*  pw      = ws + 49152;                   // NSEG*12288
    double* errpart = (double*)(ws + 147456);       // 1024 doubles
    double* n_ac    = (double*)(ws + 149504);       // 1 double

    prep_kernel<<<VOCAB / 256, 256, 0, stream>>>(embed, pack, n_ac);
    vq_scan_kernel<<<NROWS / 64, 512, 0, stream>>>(feats, pack,
                                                   quant_out, idx_out, errpart);
    seg_kernel<<<NSEG, 1024, 0, stream>>>(feats, idx_out, pcnt, pw);
    ema_kernel<<<VOCAB / 256, 256, 0, stream>>>(ema_cs, ema_w, pcnt, pw,
                                                ncs_out, nw_out, n_ac);
    final_kernel<<<VOCAB / 256, 256, 0, stream>>>(ncs_out, nw_out, n_ac, errpart,
                                                  embed_out, loss_out);
}

// Round 8
// 118.261 us; speedup vs baseline: 1.0063x; 1.0063x over previous
//
#include <hip/hip_runtime.h>
#include <math.h>

#define VOCAB 4096
#define NROWS 65536          // B*L = 4*16384
#define DECAYF 0.99f
#define EPSF 1e-5f
#define NSEG 8               // segment-sum privatization blocks

typedef unsigned long long u64;
typedef unsigned int u32;
typedef float vf2 __attribute__((ext_vector_type(2)));   // -> v_pk_*_f32

// ---------------- ws layout (floats) ----------------
// [0,      32768)   pcnt[NSEG][4096]
// [32768,  131072)  pw[NSEG][12288]
// [131072, 131584)  errpart: 256 doubles
// [131584]          counter (int)
// ~526 KB (proven ws >= 655 KB earlier)

// Fused scan: block=1024 (16 waves), grid=256 (1 block/CU). Block packs embed
// into 64 KB LDS PAIR-TRANSPOSED: pair p -> tab[2p]=(-2x0,-2x1,-2y0,-2y1),
// tab[2p+1]=(-2z0,-2z1,s0,s1). One vf2 (v_pk_fma_f32) op covers 2 candidates;
// row splats are loop-invariant. Lane owns 4 rows; wave w scans 128 pairs.
// Exact np.argmin via u64 keys. Per-half pk math is bit-identical to the
// proven scalar chain: fmaf(z',f2,fmaf(y',f1,x'*f0)); (fs+t)+s.
__global__ __launch_bounds__(1024) void vq_scan_kernel(
    const float* __restrict__ feats,
    const float* __restrict__ embed,
    float* __restrict__ quant_out,
    float* __restrict__ idx_out,
    double* __restrict__ errpart,
    int* __restrict__ counter) {
    #pragma clang fp contract(off)
    __shared__ float4 tab[VOCAB];          // 64 KB; aliased as merge scratch later

    const int tid  = threadIdx.x;
    const int wave = tid >> 6;
    const int lane = tid & 63;

    if (blockIdx.x == 0 && tid == 0) *counter = 0;   // reset for seg_fused

    // stage pair-transposed packed table (thread handles pairs t, t+1024)
    #pragma unroll
    for (int k = 0; k < 2; ++k) {
        const int p = tid + k * 1024;      // pair id 0..2047
        const float* e = embed + p * 6;
        const float x0 = e[0], y0 = e[1], z0 = e[2];
        const float x1 = e[3], y1 = e[4], z1 = e[5];
        // numpy rounding: (x^2 + y^2) + z^2, each product rounded
        const float s0 = (x0 * x0 + y0 * y0) + z0 * z0;
        const float s1 = (x1 * x1 + y1 * y1) + z1 * z1;
        tab[2 * p]     = make_float4(-2.f * x0, -2.f * x1, -2.f * y0, -2.f * y1);
        tab[2 * p + 1] = make_float4(-2.f * z0, -2.f * z1, s0, s1);
    }

    // lane's 4 rows: 48 B contiguous = 3x float4
    const int rbase = blockIdx.x * 256 + lane * 4;
    const float4 fa = *(const float4*)(feats + rbase * 3);
    const float4 fb = *(const float4*)(feats + rbase * 3 + 4);
    const float4 fc = *(const float4*)(feats + rbase * 3 + 8);
    const float f0[4] = {fa.x, fa.w, fb.z, fc.y};
    const float f1[4] = {fa.y, fb.x, fb.w, fc.z};
    const float f2[4] = {fa.z, fb.y, fc.x, fc.w};
    vf2 f0s[4], f1s[4], f2s[4], fss[4];    // loop-invariant splats
    #pragma unroll
    for (int r = 0; r < 4; ++r) {
        const float fs = (f0[r] * f0[r] + f1[r] * f1[r]) + f2[r] * f2[r];
        f0s[r] = (vf2){f0[r], f0[r]};
        f1s[r] = (vf2){f1[r], f1[r]};
        f2s[r] = (vf2){f2[r], f2[r]};
        fss[r] = (vf2){fs, fs};
    }

    __syncthreads();

    float best[4] = {INFINITY, INFINITY, INFINITY, INFINITY};
    int   bj[4]   = {0, 0, 0, 0};          // global candidate ids
    const float4* __restrict__ wt = tab + (wave << 8);   // 128 pairs = 256 float4
    const int cw = wave << 8;              // candidate base for this wave

    #pragma unroll 2
    for (int i = 0; i < 128; ++i) {
        const float4 A = wt[2 * i];        // ds_read_b128 (broadcast)
        const float4 B = wt[2 * i + 1];    // ds_read_b128 offset:16
        const vf2 xs = (vf2){A.x, A.y};
        const vf2 ys = (vf2){A.z, A.w};
        const vf2 zs = (vf2){B.x, B.y};
        const vf2 es = (vf2){B.z, B.w};
        const int c0 = cw + 2 * i;
        #pragma unroll
        for (int r = 0; r < 4; ++r) {
            vf2 t = __builtin_elementwise_fma(zs, f2s[r],
                      __builtin_elementwise_fma(ys, f1s[r], xs * f0s[r]));
            vf2 d = (fss[r] + t) + es;     // == (fsum - 2*dot) + e2sum, per half
            if (d.x < best[r]) { best[r] = d.x; bj[r] = c0; }       // even first
            if (d.y < best[r]) { best[r] = d.y; bj[r] = c0 + 1; }   // strict <
        }
    }

    // exact-order keys: monotone(dist) high 32, global cand low 32
    u64 key[4];
    #pragma unroll
    for (int r = 0; r < 4; ++r) {
        const u32 b  = __float_as_uint(best[r]);
        const u32 mb = b ^ ((u32)((int)b >> 31) | 0x80000000u);   // total order
        key[r] = ((u64)mb << 32) | (u32)bj[r];
    }

    __syncthreads();                       // all waves done reading tab
    u64* mk = (u64*)tab;                   // [16][4][64] = 32 KB, aliases tab
    if (wave != 0) {
        #pragma unroll
        for (int r = 0; r < 4; ++r)
            mk[(wave * 4 + r) * 64 + lane] = key[r];
    }
    __syncthreads();
    if (wave == 0) {
        for (int w = 1; w < 16; ++w) {
            #pragma unroll
            for (int r = 0; r < 4; ++r) {
                const u64 k = mk[(w * 4 + r) * 64 + lane];
                key[r] = k < key[r] ? k : key[r];
            }
        }
        int cand[4];
        #pragma unroll
        for (int r = 0; r < 4; ++r) cand[r] = (int)(u32)key[r];

        *(float4*)(idx_out + rbase) =
            make_float4((float)cand[0], (float)cand[1], (float)cand[2], (float)cand[3]);

        float q[4][3];
        #pragma unroll
        for (int r = 0; r < 4; ++r) {
            q[r][0] = embed[cand[r] * 3 + 0];
            q[r][1] = embed[cand[r] * 3 + 1];
            q[r][2] = embed[cand[r] * 3 + 2];
        }
        *(float4*)(quant_out + rbase * 3)     = make_float4(q[0][0], q[0][1], q[0][2], q[1][0]);
        *(float4*)(quant_out + rbase * 3 + 4) = make_float4(q[1][1], q[1][2], q[2][0], q[2][1]);
        *(float4*)(quant_out + rbase * 3 + 8) = make_float4(q[2][2], q[3][0], q[3][1], q[3][2]);

        float err = 0.0f;
        #pragma unroll
        for (int r = 0; r < 4; ++r) {
            const float d0 = q[r][0] - f0[r], d1 = q[r][1] - f1[r], d2 = q[r][2] - f2[r];
            err += d0 * d0 + d1 * d1 + d2 * d2;
        }
        #pragma unroll
        for (int off = 32; off >= 1; off >>= 1) err += __shfl_xor(err, off);
        if (lane == 0) errpart[blockIdx.x] = (double)err;
    }
}

// Segment sums (LDS privatized) + last-block-completes tail (ema + normalize
// + loss). NSEG blocks x 1024 thr; last arriving block reduces everything.
__global__ __launch_bounds__(1024) void seg_fused_kernel(
    const float* __restrict__ feats,
    const float* __restrict__ idx_f,
    const float* __restrict__ ema_cs,
    const float* __restrict__ ema_w,
    float* __restrict__ pcnt,
    float* __restrict__ pw,
    const double* __restrict__ errpart,
    float* __restrict__ ncs_out,
    float* __restrict__ nw_out,
    float* __restrict__ embed_out,
    float* __restrict__ loss_out,
    int* __restrict__ counter) {
    #pragma clang fp contract(off)
    __shared__ float lcnt[VOCAB];          // 16 KB
    __shared__ float lw[VOCAB * 3];        // 48 KB
    __shared__ int sLast;
    const int t = threadIdx.x;
    const int b = blockIdx.x;

    #pragma unroll
    for (int i = 0; i < 4; ++i)  lcnt[t + i * 1024] = 0.0f;
    #pragma unroll
    for (int i = 0; i < 12; ++i) lw[t + i * 1024] = 0.0f;
    __syncthreads();

    #pragma unroll
    for (int i = 0; i < 8; ++i) {
        const int row = b * 8192 + i * 1024 + t;
        const int cand = (int)idx_f[row];
        atomicAdd(&lcnt[cand], 1.0f);
        atomicAdd(&lw[cand * 3 + 0], feats[row * 3 + 0]);
        atomicAdd(&lw[cand * 3 + 1], feats[row * 3 + 1]);
        atomicAdd(&lw[cand * 3 + 2], feats[row * 3 + 2]);
    }
    __syncthreads();

    #pragma unroll
    for (int i = 0; i < 4; ++i)  pcnt[b * VOCAB + t + i * 1024] = lcnt[t + i * 1024];
    #pragma unroll
    for (int i = 0; i < 12; ++i) pw[b * VOCAB * 3 + t + i * 1024] = lw[t + i * 1024];

    __threadfence();                       // release partials (device scope)
    if (t == 0) sLast = (atomicAdd(counter, 1) == NSEG - 1);
    __syncthreads();
    if (!sLast) return;
    __threadfence();                       // acquire other blocks' partials

    // ---- tail: ema + n + normalize + loss (one 1024-thread block) ----
    float ncsv[4], nwv[4][3];
    double nloc = 0.0;
    #pragma unroll
    for (int i = 0; i < 4; ++i) {
        const int v = t + i * 1024;
        float c = 0.f, w0 = 0.f, w1 = 0.f, w2 = 0.f;
        for (int bb = 0; bb < NSEG; ++bb) {    // ascending = row-ascending order
            c  += pcnt[bb * VOCAB + v];
            w0 += pw[bb * VOCAB * 3 + v * 3 + 0];
            w1 += pw[bb * VOCAB * 3 + v * 3 + 1];
            w2 += pw[bb * VOCAB * 3 + v * 3 + 2];
        }
        const float ncs = DECAYF * ema_cs[v] + (1.0f - DECAYF) * c;
        const float n0  = DECAYF * ema_w[v * 3 + 0] + (1.0f - DECAYF) * w0;
        const float n1  = DECAYF * ema_w[v * 3 + 1] + (1.0f - DECAYF) * w1;
        const float n2  = DECAYF * ema_w[v * 3 + 2] + (1.0f - DECAYF) * w2;
        ncs_out[v] = ncs;
        nw_out[v * 3 + 0] = n0;
        nw_out[v * 3 + 1] = n1;
        nw_out[v * 3 + 2] = n2;
        ncsv[i] = ncs; nwv[i][0] = n0; nwv[i][1] = n1; nwv[i][2] = n2;
        nloc += (double)ncs;
    }
    // block-reduce n (double)
    #pragma unroll
    for (int off = 32; off >= 1; off >>= 1) nloc += __shfl_xor(nloc, off);
    __syncthreads();                       // lcnt/lw free for reuse
    double* nds = (double*)lw;             // 16 doubles
    if ((t & 63) == 0) nds[t >> 6] = nloc;
    __syncthreads();
    double n = 0.0;
    #pragma unroll
    for (int w = 0; w < 16; ++w) n += nds[w];
    const float nf = (float)n;

    #pragma unroll
    for (int i = 0; i < 4; ++i) {
        const int v = t + i * 1024;
        const float cs = (ncsv[i] + EPSF) / (nf + (float)VOCAB * EPSF) * nf;
        const float d0 = nwv[i][0] / cs;
        const float d1 = nwv[i][1] / cs;
        const float d2 = nwv[i][2] / cs;
        const float nrm = fmaxf(sqrtf(d1 * d1 + d2 * d2), EPSF);
        embed_out[v * 3 + 0] = d0;
        embed_out[v * 3 + 1] = d1 / nrm;
        embed_out[v * 3 + 2] = d2 / nrm;
    }

    // loss from 256 scan partials
    __syncthreads();
    double* se = (double*)lcnt;            // 256 doubles
    if (t < 256) se[t] = errpart[t];
    __syncthreads();
    #pragma unroll
    for (int s = 128; s > 0; s >>= 1) {
        if (t < s) se[t] += se[t + s];
        __syncthreads();
    }
    if (t == 0)
        loss_out[0] = (float)(1.25 * se[0] / (double)(NROWS * 3));
}

extern "C" void kernel_launch(void* const* d_in, const int* in_sizes, int n_in,
                              void* d_out, int out_size, void* d_ws, size_t ws_size,
                              hipStream_t stream) {
    const float* feats  = (const float*)d_in[0];   // 65536*3
    const float* embed  = (const float*)d_in[1];   // 4096*3
    const float* ema_cs = (const float*)d_in[2];   // 4096
    const float* ema_w  = (const float*)d_in[3];   // 4096*3

    float* out = (float*)d_out;
    float* quant_out = out;                         // 196608
    float* idx_out   = out + 196608;                // 65536
    float* loss_out  = out + 262144;                // 1
    float* embed_out = out + 262145;                // 12288
    float* ncs_out   = out + 274433;                // 4096
    float* nw_out    = out + 278529;                // 12288

    float* ws = (float*)d_ws;
    float*  pcnt    = ws;                           // NSEG*4096
    float*  pw      = ws + 32768;                   // NSEG*12288
    double* errpart = (double*)(ws + 131072);       // 256 doubles
    int*    counter = (int*)(ws + 131584);          // 1 int

    vq_scan_kernel<<<NROWS / 256, 1024, 0, stream>>>(feats, embed,
                                                     quant_out, idx_out,
                                                     errpart, counter);
    seg_fused_kernel<<<NSEG, 1024, 0, stream>>>(feats, idx_out, ema_cs, ema_w,
                                                pcnt, pw, errpart,
                                                ncs_out, nw_out, embed_out,
                                                loss_out, counter);
}

// Round 9
// 80.022 us; speedup vs baseline: 1.4871x; 1.4779x over previous
//
#include <hip/hip_runtime.h>
#include <math.h>

#define VOCAB 4096
#define NROWS 65536          // B*L = 4*16384
#define DECAYF 0.99f
#define EPSF 1e-5f

typedef unsigned long long u64;
typedef unsigned int u32;
typedef float vf2 __attribute__((ext_vector_type(2)));   // -> v_pk_*_f32

// ---------------- ws layout (bytes) ----------------
// [0,    2048)  errpart: 256 doubles
// [2048, 2056)  n_acc double
// [4096, 4096 + NSEG*VOCAB*16)  part[NSEG][VOCAB] float4 (cnt,w0,w1,w2)
// NSEG picked from ws_size (>=8 proven safe; 64 if ws allows 4 MB)

// Fused scan: block=1024 (16 waves), grid=256. Block packs embed into 64 KB
// LDS PAIR-TRANSPOSED: pair p -> tab[2p]=(-2x0,-2x1,-2y0,-2y1),
// tab[2p+1]=(-2z0,-2z1,s0,s1). One v_pk_fma_f32 covers 2 candidates; row
// splats loop-invariant. Lane owns 4 rows; wave w scans 128 pairs. Exact
// np.argmin via u64 keys (monotone dist | cand). Per-half pk math is
// bit-identical to the proven scalar chain.
__global__ __launch_bounds__(1024) void vq_scan_kernel(
    const float* __restrict__ feats,
    const float* __restrict__ embed,
    float* __restrict__ quant_out,
    float* __restrict__ idx_out,
    double* __restrict__ errpart,
    double* __restrict__ n_acc) {
    #pragma clang fp contract(off)
    __shared__ float4 tab[VOCAB];          // 64 KB; aliased as merge scratch later

    const int tid  = threadIdx.x;
    const int wave = tid >> 6;
    const int lane = tid & 63;

    if (blockIdx.x == 0 && tid == 0) *n_acc = 0.0;   // fresh accumulator per call

    // stage pair-transposed packed table (thread handles pairs t, t+1024)
    #pragma unroll
    for (int k = 0; k < 2; ++k) {
        const int p = tid + k * 1024;      // pair id 0..2047
        const float* e = embed + p * 6;
        const float x0 = e[0], y0 = e[1], z0 = e[2];
        const float x1 = e[3], y1 = e[4], z1 = e[5];
        // numpy rounding: (x^2 + y^2) + z^2, each product rounded
        const float s0 = (x0 * x0 + y0 * y0) + z0 * z0;
        const float s1 = (x1 * x1 + y1 * y1) + z1 * z1;
        tab[2 * p]     = make_float4(-2.f * x0, -2.f * x1, -2.f * y0, -2.f * y1);
        tab[2 * p + 1] = make_float4(-2.f * z0, -2.f * z1, s0, s1);
    }

    // lane's 4 rows: 48 B contiguous = 3x float4
    const int rbase = blockIdx.x * 256 + lane * 4;
    const float4 fa = *(const float4*)(feats + rbase * 3);
    const float4 fb = *(const float4*)(feats + rbase * 3 + 4);
    const float4 fc = *(const float4*)(feats + rbase * 3 + 8);
    const float f0[4] = {fa.x, fa.w, fb.z, fc.y};
    const float f1[4] = {fa.y, fb.x, fb.w, fc.z};
    const float f2[4] = {fa.z, fb.y, fc.x, fc.w};
    vf2 f0s[4], f1s[4], f2s[4], fss[4];    // loop-invariant splats
    #pragma unroll
    for (int r = 0; r < 4; ++r) {
        const float fs = (f0[r] * f0[r] + f1[r] * f1[r]) + f2[r] * f2[r];
        f0s[r] = (vf2){f0[r], f0[r]};
        f1s[r] = (vf2){f1[r], f1[r]};
        f2s[r] = (vf2){f2[r], f2[r]};
        fss[r] = (vf2){fs, fs};
    }

    __syncthreads();

    float best[4] = {INFINITY, INFINITY, INFINITY, INFINITY};
    int   bj[4]   = {0, 0, 0, 0};          // global candidate ids
    const float4* __restrict__ wt = tab + (wave << 8);   // 128 pairs = 256 float4
    const int cw = wave << 8;              // candidate base for this wave

    #pragma unroll 2
    for (int i = 0; i < 128; ++i) {
        const float4 A = wt[2 * i];        // ds_read_b128 (broadcast)
        const float4 B = wt[2 * i + 1];    // ds_read_b128 offset:16
        const vf2 xs = (vf2){A.x, A.y};
        const vf2 ys = (vf2){A.z, A.w};
        const vf2 zs = (vf2){B.x, B.y};
        const vf2 es = (vf2){B.z, B.w};
        const int c0 = cw + 2 * i;
        #pragma unroll
        for (int r = 0; r < 4; ++r) {
            vf2 t = __builtin_elementwise_fma(zs, f2s[r],
                      __builtin_elementwise_fma(ys, f1s[r], xs * f0s[r]));
            vf2 d = (fss[r] + t) + es;     // == (fsum - 2*dot) + e2sum, per half
            if (d.x < best[r]) { best[r] = d.x; bj[r] = c0; }       // even first
            if (d.y < best[r]) { best[r] = d.y; bj[r] = c0 + 1; }   // strict <
        }
    }

    // exact-order keys: monotone(dist) high 32, global cand low 32
    u64 key[4];
    #pragma unroll
    for (int r = 0; r < 4; ++r) {
        const u32 b  = __float_as_uint(best[r]);
        const u32 mb = b ^ ((u32)((int)b >> 31) | 0x80000000u);   // total order
        key[r] = ((u64)mb << 32) | (u32)bj[r];
    }

    __syncthreads();                       // all waves done reading tab
    u64* mk = (u64*)tab;                   // [16][4][64] = 32 KB, aliases tab
    if (wave != 0) {
        #pragma unroll
        for (int r = 0; r < 4; ++r)
            mk[(wave * 4 + r) * 64 + lane] = key[r];
    }
    __syncthreads();
    if (wave == 0) {
        for (int w = 1; w < 16; ++w) {
            #pragma unroll
            for (int r = 0; r < 4; ++r) {
                const u64 k = mk[(w * 4 + r) * 64 + lane];
                key[r] = k < key[r] ? k : key[r];
            }
        }
        int cand[4];
        #pragma unroll
        for (int r = 0; r < 4; ++r) cand[r] = (int)(u32)key[r];

        *(float4*)(idx_out + rbase) =
            make_float4((float)cand[0], (float)cand[1], (float)cand[2], (float)cand[3]);

        float q[4][3];
        #pragma unroll
        for (int r = 0; r < 4; ++r) {
            q[r][0] = embed[cand[r] * 3 + 0];
            q[r][1] = embed[cand[r] * 3 + 1];
            q[r][2] = embed[cand[r] * 3 + 2];
        }
        *(float4*)(quant_out + rbase * 3)     = make_float4(q[0][0], q[0][1], q[0][2], q[1][0]);
        *(float4*)(quant_out + rbase * 3 + 4) = make_float4(q[1][1], q[1][2], q[2][0], q[2][1]);
        *(float4*)(quant_out + rbase * 3 + 8) = make_float4(q[2][2], q[3][0], q[3][1], q[3][2]);

        float err = 0.0f;
        #pragma unroll
        for (int r = 0; r < 4; ++r) {
            const float d0 = q[r][0] - f0[r], d1 = q[r][1] - f1[r], d2 = q[r][2] - f2[r];
            err += d0 * d0 + d1 * d1 + d2 * d2;
        }
        #pragma unroll
        for (int off = 32; off >= 1; off >>= 1) err += __shfl_xor(err, off);
        if (lane == 0) errpart[blockIdx.x] = (double)err;
    }
}

// Segment sums, LDS-privatized: NSEG blocks x 1024 thr, each block handles
// NROWS/NSEG rows, flushes per-v packed float4 partial (cnt,w0,w1,w2).
// No fences, no global atomics.
__global__ __launch_bounds__(1024) void seg_kernel(
    const float* __restrict__ feats,
    const float* __restrict__ idx_f,
    float4* __restrict__ part,
    int iters) {
    __shared__ float lcnt[VOCAB];          // 16 KB
    __shared__ float lw[VOCAB * 3];        // 48 KB
    const int t = threadIdx.x;
    const int b = blockIdx.x;

    #pragma unroll
    for (int i = 0; i < 4; ++i)  lcnt[t + i * 1024] = 0.0f;
    #pragma unroll
    for (int i = 0; i < 12; ++i) lw[t + i * 1024] = 0.0f;
    __syncthreads();

    const int base = b * iters * 1024;
    for (int i = 0; i < iters; ++i) {
        const int row = base + i * 1024 + t;
        const int cand = (int)idx_f[row];
        atomicAdd(&lcnt[cand], 1.0f);
        atomicAdd(&lw[cand * 3 + 0], feats[row * 3 + 0]);
        atomicAdd(&lw[cand * 3 + 1], feats[row * 3 + 1]);
        atomicAdd(&lw[cand * 3 + 2], feats[row * 3 + 2]);
    }
    __syncthreads();

    #pragma unroll
    for (int i = 0; i < 4; ++i) {
        const int v = t + i * 1024;
        part[b * VOCAB + v] = make_float4(lcnt[v], lw[3 * v], lw[3 * v + 1], lw[3 * v + 2]);
    }
}

// Reduce partials (ascending b = ascending-row order) + EMA + n + loss.
__global__ __launch_bounds__(256) void ema_reduce_kernel(
    const float4* __restrict__ part,
    const float* __restrict__ ema_cs,
    const float* __restrict__ ema_w,
    const double* __restrict__ errpart,
    float* __restrict__ ncs_out,
    float* __restrict__ nw_out,
    double* __restrict__ n_acc,
    float* __restrict__ loss_out,
    int nseg) {
    const int v = blockIdx.x * 256 + threadIdx.x;
    float c = 0.f, w0 = 0.f, w1 = 0.f, w2 = 0.f;
    for (int b = 0; b < nseg; ++b) {
        const float4 p = part[b * VOCAB + v];
        c += p.x; w0 += p.y; w1 += p.z; w2 += p.w;
    }
    const float ncs = DECAYF * ema_cs[v] + (1.0f - DECAYF) * c;
    ncs_out[v] = ncs;
    nw_out[v * 3 + 0] = DECAYF * ema_w[v * 3 + 0] + (1.0f - DECAYF) * w0;
    nw_out[v * 3 + 1] = DECAYF * ema_w[v * 3 + 1] + (1.0f - DECAYF) * w1;
    nw_out[v * 3 + 2] = DECAYF * ema_w[v * 3 + 2] + (1.0f - DECAYF) * w2;

    double nloc = (double)ncs;
    #pragma unroll
    for (int off = 32; off >= 1; off >>= 1) nloc += __shfl_xor(nloc, off);
    if ((threadIdx.x & 63) == 0) atomicAdd(n_acc, nloc);

    if (blockIdx.x == 0) {                 // loss from the 256 scan partials
        __shared__ double se[256];
        const int t = threadIdx.x;
        se[t] = errpart[t];
        __syncthreads();
        #pragma unroll
        for (int s = 128; s > 0; s >>= 1) {
            if (t < s) se[t] += se[t + s];
            __syncthreads();
        }
        if (t == 0)
            loss_out[0] = (float)(1.25 * se[0] / (double)(NROWS * 3));
    }
}

__global__ __launch_bounds__(256) void final_kernel(
    const float* __restrict__ ncs,
    const float* __restrict__ nw,
    const double* __restrict__ n_acc,
    float* __restrict__ embed_out) {
    const int v = blockIdx.x * 256 + threadIdx.x;
    const float n = (float)(*n_acc);
    const float cs = (ncs[v] + EPSF) / (n + (float)VOCAB * EPSF) * n;
    const float d0 = nw[v * 3 + 0] / cs;
    const float d1 = nw[v * 3 + 1] / cs;
    const float d2 = nw[v * 3 + 2] / cs;
    const float nrm = fmaxf(sqrtf(d1 * d1 + d2 * d2), EPSF);
    embed_out[v * 3 + 0] = d0;
    embed_out[v * 3 + 1] = d1 / nrm;
    embed_out[v * 3 + 2] = d2 / nrm;
}

extern "C" void kernel_launch(void* const* d_in, const int* in_sizes, int n_in,
                              void* d_out, int out_size, void* d_ws, size_t ws_size,
                              hipStream_t stream) {
    const float* feats  = (const float*)d_in[0];   // 65536*3
    const float* embed  = (const float*)d_in[1];   // 4096*3
    const float* ema_cs = (const float*)d_in[2];   // 4096
    const float* ema_w  = (const float*)d_in[3];   // 4096*3

    float* out = (float*)d_out;
    float* quant_out = out;                         // 196608
    float* idx_out   = out + 196608;                // 65536
    float* loss_out  = out + 262144;                // 1
    float* embed_out = out + 262145;                // 12288
    float* ncs_out   = out + 274433;                // 4096
    float* nw_out    = out + 278529;                // 12288

    char* wsb = (char*)d_ws;
    double* errpart = (double*)wsb;                 // 256 doubles
    double* n_ac    = (double*)(wsb + 2048);        // 1 double
    float4* part    = (float4*)(wsb + 4096);        // NSEG*4096 float4

    // NSEG from ws_size (deterministic; >=8 proven safe at 512 KB + 4 KB)
    const size_t per_seg = (size_t)VOCAB * 16;
    const size_t avail = ws_size > 4096 ? ws_size - 4096 : 0;
    int nseg = 8;
    if (avail >= 64 * per_seg)      nseg = 64;
    else if (avail >= 32 * per_seg) nseg = 32;
    else if (avail >= 16 * per_seg) nseg = 16;
    const int iters = NROWS / (nseg * 1024);

    vq_scan_kernel<<<NROWS / 256, 1024, 0, stream>>>(feats, embed,
                                                     quant_out, idx_out,
                                                     errpart, n_ac);
    seg_kernel<<<nseg, 1024, 0, stream>>>(feats, idx_out, part, iters);
    ema_reduce_kernel<<<VOCAB / 256, 256, 0, stream>>>(part, ema_cs, ema_w,
                                                       errpart, ncs_out, nw_out,
                                                       n_ac, loss_out, nseg);
    final_kernel<<<VOCAB / 256, 256, 0, stream>>>(ncs_out, nw_out, n_ac, embed_out);
}

// Round 10
// 64.224 us; speedup vs baseline: 1.8529x; 1.2460x over previous
//
#include <hip/hip_runtime.h>
#include <math.h>

#define VOCAB 4096
#define NROWS 65536          // B*L = 4*16384
#define DECAYF 0.99f
#define EPSF 1e-5f

typedef unsigned long long u64;
typedef unsigned int u32;
typedef float vf2 __attribute__((ext_vector_type(2)));   // -> v_pk_*_f32

// ---------------- ws layout (bytes) ----------------
// [0,    2048)  errpart: 256 doubles
// [2048, 2052)  n value (float), written by seg's extra block
// [4096, 4096 + NSEG*VOCAB*16)  part[NSEG][VOCAB] float4 (cnt,w0,w1,w2)

// Scan: block=1024 (16 waves), grid=256. Block packs embed into 64 KB LDS
// pair-transposed (pair p: tab[2p]=(-2x0,-2x1,-2y0,-2y1),
// tab[2p+1]=(-2z0,-2z1,s0,s1)). Lane owns 4 rows; wave w scans 256 cands as
// 32 GROUPS of 8: per group 4 pk-dist pairs -> pk_min tree -> ONE strict-<
// select (group base only). Post-scan recovery re-reads the winning group and
// recomputes dists bit-identically to find the exact first-min index
// (= np.argmin tie-break). u64 (monotone dist | idx) cross-wave merge.
__global__ __launch_bounds__(1024, 4) void vq_scan_kernel(
    const float* __restrict__ feats,
    const float* __restrict__ embed,
    float* __restrict__ quant_out,
    float* __restrict__ idx_out,
    double* __restrict__ errpart) {
    #pragma clang fp contract(off)
    __shared__ float4 tab[VOCAB];          // 64 KB; aliased as merge scratch later

    const int tid  = threadIdx.x;
    const int wave = tid >> 6;
    const int lane = tid & 63;

    // stage pair-transposed packed table (thread handles pairs t, t+1024)
    #pragma unroll
    for (int k = 0; k < 2; ++k) {
        const int p = tid + k * 1024;      // pair id 0..2047
        const float* e = embed + p * 6;
        const float x0 = e[0], y0 = e[1], z0 = e[2];
        const float x1 = e[3], y1 = e[4], z1 = e[5];
        // numpy rounding: (x^2 + y^2) + z^2, each product rounded
        const float s0 = (x0 * x0 + y0 * y0) + z0 * z0;
        const float s1 = (x1 * x1 + y1 * y1) + z1 * z1;
        tab[2 * p]     = make_float4(-2.f * x0, -2.f * x1, -2.f * y0, -2.f * y1);
        tab[2 * p + 1] = make_float4(-2.f * z0, -2.f * z1, s0, s1);
    }

    // lane's 4 rows: 48 B contiguous = 3x float4
    const int rbase = blockIdx.x * 256 + lane * 4;
    const float4 fa = *(const float4*)(feats + rbase * 3);
    const float4 fb = *(const float4*)(feats + rbase * 3 + 4);
    const float4 fc = *(const float4*)(feats + rbase * 3 + 8);
    const float f0[4] = {fa.x, fa.w, fb.z, fc.y};
    const float f1[4] = {fa.y, fb.x, fb.w, fc.z};
    const float f2[4] = {fa.z, fb.y, fc.x, fc.w};
    vf2 f0s[4], f1s[4], f2s[4], fss[4];    // loop-invariant splats
    #pragma unroll
    for (int r = 0; r < 4; ++r) {
        const float fs = (f0[r] * f0[r] + f1[r] * f1[r]) + f2[r] * f2[r];
        f0s[r] = (vf2){f0[r], f0[r]};
        f1s[r] = (vf2){f1[r], f1[r]};
        f2s[r] = (vf2){f2[r], f2[r]};
        fss[r] = (vf2){fs, fs};
    }

    __syncthreads();

    float best[4] = {INFINITY, INFINITY, INFINITY, INFINITY};
    int   gb[4]   = {0, 0, 0, 0};          // winning group's base (global float4/cand idx)
    const float4* __restrict__ wt = tab + (wave << 8);   // 256 float4 = 256 cands
    const int cw = wave << 8;              // candidate base for this wave

    for (int g = 0; g < 32; ++g) {         // 32 groups of 8 cands
        const float4 A0 = wt[8 * g + 0], B0 = wt[8 * g + 1];
        const float4 A1 = wt[8 * g + 2], B1 = wt[8 * g + 3];
        const float4 A2 = wt[8 * g + 4], B2 = wt[8 * g + 5];
        const float4 A3 = wt[8 * g + 6], B3 = wt[8 * g + 7];
        const vf2 xs0 = {A0.x, A0.y}, ys0 = {A0.z, A0.w}, zs0 = {B0.x, B0.y}, es0 = {B0.z, B0.w};
        const vf2 xs1 = {A1.x, A1.y}, ys1 = {A1.z, A1.w}, zs1 = {B1.x, B1.y}, es1 = {B1.z, B1.w};
        const vf2 xs2 = {A2.x, A2.y}, ys2 = {A2.z, A2.w}, zs2 = {B2.x, B2.y}, es2 = {B2.z, B2.w};
        const vf2 xs3 = {A3.x, A3.y}, ys3 = {A3.z, A3.w}, zs3 = {B3.x, B3.y}, es3 = {B3.z, B3.w};
        const int cbase = cw + 8 * g;
        #pragma unroll
        for (int r = 0; r < 4; ++r) {
            // per half: fmaf(z',f2,fmaf(y',f1,x'*f0)); (fs+t)+s  (ref-exact)
            vf2 t0 = __builtin_elementwise_fma(zs0, f2s[r], __builtin_elementwise_fma(ys0, f1s[r], xs0 * f0s[r]));
            vf2 t1 = __builtin_elementwise_fma(zs1, f2s[r], __builtin_elementwise_fma(ys1, f1s[r], xs1 * f0s[r]));
            vf2 t2 = __builtin_elementwise_fma(zs2, f2s[r], __builtin_elementwise_fma(ys2, f1s[r], xs2 * f0s[r]));
            vf2 t3 = __builtin_elementwise_fma(zs3, f2s[r], __builtin_elementwise_fma(ys3, f1s[r], xs3 * f0s[r]));
            vf2 d0 = (fss[r] + t0) + es0;
            vf2 d1 = (fss[r] + t1) + es1;
            vf2 d2 = (fss[r] + t2) + es2;
            vf2 d3 = (fss[r] + t3) + es3;
            vf2 m01 = __builtin_elementwise_min(d0, d1);
            vf2 m23 = __builtin_elementwise_min(d2, d3);
            vf2 m   = __builtin_elementwise_min(m01, m23);
            const float m8 = fminf(m.x, m.y);
            if (m8 < best[r]) { best[r] = m8; gb[r] = cbase; }   // strict <
        }
    }

    // ---- recovery: find exact first index inside each row's winning group ----
    u64 key[4];
    #pragma unroll
    for (int r = 0; r < 4; ++r) {
        const int b0 = gb[r];              // global cand base (also tab index)
        const float bv = best[r];
        int idx = b0;
        #pragma unroll
        for (int k = 3; k >= 0; --k) {     // descending -> lowest index wins
            const float4 A = tab[b0 + 2 * k];
            const float4 B = tab[b0 + 2 * k + 1];
            const vf2 xs = {A.x, A.y}, ys = {A.z, A.w}, zs = {B.x, B.y}, es = {B.z, B.w};
            vf2 t = __builtin_elementwise_fma(zs, f2s[r], __builtin_elementwise_fma(ys, f1s[r], xs * f0s[r]));
            vf2 d = (fss[r] + t) + es;     // bit-identical to scan path
            if (d.y == bv) idx = b0 + 2 * k + 1;
            if (d.x == bv) idx = b0 + 2 * k;
        }
        const u32 bb = __float_as_uint(bv);
        const u32 mb = bb ^ ((u32)((int)bb >> 31) | 0x80000000u);   // total order
        key[r] = ((u64)mb << 32) | (u32)idx;
    }

    __syncthreads();                       // all waves done reading tab
    u64* mk = (u64*)tab;                   // [16][4][64] = 32 KB, aliases tab
    if (wave != 0) {
        #pragma unroll
        for (int r = 0; r < 4; ++r)
            mk[(wave * 4 + r) * 64 + lane] = key[r];
    }
    __syncthreads();
    if (wave == 0) {
        for (int w = 1; w < 16; ++w) {
            #pragma unroll
            for (int r = 0; r < 4; ++r) {
                const u64 k = mk[(w * 4 + r) * 64 + lane];
                key[r] = k < key[r] ? k : key[r];
            }
        }
        int cand[4];
        #pragma unroll
        for (int r = 0; r < 4; ++r) cand[r] = (int)(u32)key[r];

        *(float4*)(idx_out + rbase) =
            make_float4((float)cand[0], (float)cand[1], (float)cand[2], (float)cand[3]);

        float q[4][3];
        #pragma unroll
        for (int r = 0; r < 4; ++r) {
            q[r][0] = embed[cand[r] * 3 + 0];
            q[r][1] = embed[cand[r] * 3 + 1];
            q[r][2] = embed[cand[r] * 3 + 2];
        }
        *(float4*)(quant_out + rbase * 3)     = make_float4(q[0][0], q[0][1], q[0][2], q[1][0]);
        *(float4*)(quant_out + rbase * 3 + 4) = make_float4(q[1][1], q[1][2], q[2][0], q[2][1]);
        *(float4*)(quant_out + rbase * 3 + 8) = make_float4(q[2][2], q[3][0], q[3][1], q[3][2]);

        float err = 0.0f;
        #pragma unroll
        for (int r = 0; r < 4; ++r) {
            const float d0 = q[r][0] - f0[r], d1 = q[r][1] - f1[r], d2 = q[r][2] - f2[r];
            err += d0 * d0 + d1 * d1 + d2 * d2;
        }
        #pragma unroll
        for (int off = 32; off >= 1; off >>= 1) err += __shfl_xor(err, off);
        if (lane == 0) errpart[blockIdx.x] = (double)err;
    }
}

// Segment sums, LDS-privatized; blocks [0,nseg) accumulate partials; the extra
// block (== nseg) computes n = DECAY*sum(ema_cs) + (1-DECAY)*NROWS.
__global__ __launch_bounds__(1024) void seg_kernel(
    const float* __restrict__ feats,
    const float* __restrict__ idx_f,
    const float* __restrict__ ema_cs,
    float4* __restrict__ part,
    float* __restrict__ n_out,
    int iters, int nseg) {
    __shared__ float lcnt[VOCAB];          // 16 KB
    __shared__ float lw[VOCAB * 3];        // 48 KB
    const int t = threadIdx.x;
    const int b = blockIdx.x;

    if (b == nseg) {                       // n block (input-only reduction)
        float s = ema_cs[t] + ema_cs[t + 1024] + ema_cs[t + 2048] + ema_cs[t + 3072];
        #pragma unroll
        for (int off = 32; off >= 1; off >>= 1) s += __shfl_xor(s, off);
        if ((t & 63) == 0) lcnt[t >> 6] = s;
        __syncthreads();
        if (t == 0) {
            float S = 0.f;
            #pragma unroll
            for (int w = 0; w < 16; ++w) S += lcnt[w];
            *n_out = DECAYF * S + (1.0f - DECAYF) * (float)NROWS;
        }
        return;
    }

    #pragma unroll
    for (int i = 0; i < 4; ++i)  lcnt[t + i * 1024] = 0.0f;
    #pragma unroll
    for (int i = 0; i < 12; ++i) lw[t + i * 1024] = 0.0f;
    __syncthreads();

    const int base = b * iters * 1024;
    for (int i = 0; i < iters; ++i) {
        const int row = base + i * 1024 + t;
        const int cand = (int)idx_f[row];
        atomicAdd(&lcnt[cand], 1.0f);
        atomicAdd(&lw[cand * 3 + 0], feats[row * 3 + 0]);
        atomicAdd(&lw[cand * 3 + 1], feats[row * 3 + 1]);
        atomicAdd(&lw[cand * 3 + 2], feats[row * 3 + 2]);
    }
    __syncthreads();

    #pragma unroll
    for (int i = 0; i < 4; ++i) {
        const int v = t + i * 1024;
        part[b * VOCAB + v] = make_float4(lcnt[v], lw[3 * v], lw[3 * v + 1], lw[3 * v + 2]);
    }
}

// Reduce partials (ascending b = row-ascending order) + EMA + normalize + loss.
__global__ __launch_bounds__(256) void ema_final_kernel(
    const float4* __restrict__ part,
    const float* __restrict__ ema_cs,
    const float* __restrict__ ema_w,
    const double* __restrict__ errpart,
    const float* __restrict__ n_out,
    float* __restrict__ ncs_out,
    float* __restrict__ nw_out,
    float* __restrict__ embed_out,
    float* __restrict__ loss_out,
    int nseg) {
    const int v = blockIdx.x * 256 + threadIdx.x;
    float c = 0.f, w0 = 0.f, w1 = 0.f, w2 = 0.f;
    for (int b = 0; b < nseg; ++b) {
        const float4 p = part[b * VOCAB + v];
        c += p.x; w0 += p.y; w1 += p.z; w2 += p.w;
    }
    const float ncs = DECAYF * ema_cs[v] + (1.0f - DECAYF) * c;
    const float n0  = DECAYF * ema_w[v * 3 + 0] + (1.0f - DECAYF) * w0;
    const float n1  = DECAYF * ema_w[v * 3 + 1] + (1.0f - DECAYF) * w1;
    const float n2  = DECAYF * ema_w[v * 3 + 2] + (1.0f - DECAYF) * w2;
    ncs_out[v] = ncs;
    nw_out[v * 3 + 0] = n0;
    nw_out[v * 3 + 1] = n1;
    nw_out[v * 3 + 2] = n2;

    const float n = *n_out;
    const float cs = (ncs + EPSF) / (n + (float)VOCAB * EPSF) * n;
    const float d0 = n0 / cs;
    const float d1 = n1 / cs;
    const float d2 = n2 / cs;
    const float nrm = fmaxf(sqrtf(d1 * d1 + d2 * d2), EPSF);
    embed_out[v * 3 + 0] = d0;
    embed_out[v * 3 + 1] = d1 / nrm;
    embed_out[v * 3 + 2] = d2 / nrm;

    if (blockIdx.x == 0) {                 // loss from the 256 scan partials
        __shared__ double se[256];
        const int t = threadIdx.x;
        se[t] = errpart[t];
        __syncthreads();
        #pragma unroll
        for (int s = 128; s > 0; s >>= 1) {
            if (t < s) se[t] += se[t + s];
            __syncthreads();
        }
        if (t == 0)
            loss_out[0] = (float)(1.25 * se[0] / (double)(NROWS * 3));
    }
}

extern "C" void kernel_launch(void* const* d_in, const int* in_sizes, int n_in,
                              void* d_out, int out_size, void* d_ws, size_t ws_size,
                              hipStream_t stream) {
    const float* feats  = (const float*)d_in[0];   // 65536*3
    const float* embed  = (const float*)d_in[1];   // 4096*3
    const float* ema_cs = (const float*)d_in[2];   // 4096
    const float* ema_w  = (const float*)d_in[3];   // 4096*3

    float* out = (float*)d_out;
    float* quant_out = out;                         // 196608
    float* idx_out   = out + 196608;                // 65536
    float* loss_out  = out + 262144;                // 1
    float* embed_out = out + 262145;                // 12288
    float* ncs_out   = out + 274433;                // 4096
    float* nw_out    = out + 278529;                // 12288

    char* wsb = (char*)d_ws;
    double* errpart = (double*)wsb;                 // 256 doubles
    float*  n_out   = (float*)(wsb + 2048);         // 1 float
    float4* part    = (float4*)(wsb + 4096);        // NSEG*4096 float4

    // NSEG from ws_size (deterministic; 8 proven safe at ~516 KB)
    const size_t per_seg = (size_t)VOCAB * 16;
    const size_t avail = ws_size > 4096 ? ws_size - 4096 : 0;
    int nseg = 8;
    if (avail >= 64 * per_seg)      nseg = 64;
    else if (avail >= 32 * per_seg) nseg = 32;
    else if (avail >= 16 * per_seg) nseg = 16;
    const int iters = NROWS / (nseg * 1024);

    vq_scan_kernel<<<NROWS / 256, 1024, 0, stream>>>(feats, embed,
                                                     quant_out, idx_out, errpart);
    seg_kernel<<<nseg + 1, 1024, 0, stream>>>(feats, idx_out, ema_cs,
                                              part, n_out, iters, nseg);
    ema_final_kernel<<<VOCAB / 256, 256, 0, stream>>>(part, ema_cs, ema_w,
                                                      errpart, n_out,
                                                      ncs_out, nw_out, embed_out,
                                                      loss_out, nseg);
}